// Round 9
// baseline (349.939 us; speedup 1.0000x reference)
//
#include <hip/hip_runtime.h>
#include <hip/hip_bf16.h>
#include <type_traits>

// Problem constants
#define DIMN   2048
#define NH     16
#define NKVH   4
#define HD     128
#define KVD    512        // NKVH*HD
#define NQKV   3072       // DIMN + 2*KVD
#define BATCH  2
#define SEQ    2048
#define MROWS  4096       // BATCH*SEQ
#define VOFF   2560       // DIMN + KVD: v offset inside qkv row

typedef __attribute__((ext_vector_type(8))) __bf16 bf16x8;
typedef __attribute__((ext_vector_type(4))) float floatx4;

#define BIG_NEG (-1.0e30f)

// hardware RTNE f32->bf16 (v_cvt_pk_bf16_f32)
__device__ __forceinline__ short bf16rn(float f) {
  union { __bf16 h; short s; } u;
  u.h = (__bf16)f;
  return u.s;
}
__device__ __forceinline__ float bf2f(short s) {
  union { unsigned u; float f; } v;
  v.u = ((unsigned)(unsigned short)s) << 16;
  return v.f;
}
__device__ __forceinline__ unsigned pack2bf(float a, float b) {
  return (unsigned)(unsigned short)bf16rn(a) |
         ((unsigned)(unsigned short)bf16rn(b) << 16);
}

// async 16B global -> LDS. LDS dest = wave-uniform base + lane*16 B;
// one instruction covers 64 lanes * 16 B = 512 shorts.
__device__ __forceinline__ void async_cp16(const short* g, short* l) {
  __builtin_amdgcn_global_load_lds(
      (const __attribute__((address_space(1))) unsigned int*)g,
      (__attribute__((address_space(3))) unsigned int*)l, 16, 0, 0);
}

// ---------------------------------------------------------------- f32 -> bf16
__global__ void f32_to_bf16_kern(const float* __restrict__ in,
                                 short* __restrict__ out, int n8) {
  int i = blockIdx.x * blockDim.x + threadIdx.x;
  if (i >= n8) return;
  float4 a = ((const float4*)in)[i * 2];
  float4 b = ((const float4*)in)[i * 2 + 1];
  short r[8];
  r[0] = bf16rn(a.x); r[1] = bf16rn(a.y); r[2] = bf16rn(a.z); r[3] = bf16rn(a.w);
  r[4] = bf16rn(b.x); r[5] = bf16rn(b.y); r[6] = bf16rn(b.z); r[7] = bf16rn(b.w);
  ((uint4*)out)[i] = *(const uint4*)r;
}

// --------------------------------------------------- C[M][N] = A[M][K] B[N][K]^T
// 128x128 tile, BK=32, double-buffered global_load_lds staging, one barrier per
// K-iter. XOR-swizzled LDS (stored chunk = logical ^ (row&3)). OUT: float or
// bf16 (short) epilogue. (Used for the proj GEMM; natural n&7 XCD mapping keeps
// B-panels L2-resident - R7/R8 measured.)
template <typename OUT>
__global__ __launch_bounds__(256) void gemm_bt_as(const short* __restrict__ A,
                                                  const short* __restrict__ Bw,
                                                  OUT* __restrict__ C,
                                                  int N, int K) {
  __shared__ __align__(16) short As[2][128 * 32];
  __shared__ __align__(16) short Bs[2][128 * 32];
  const int t = threadIdx.x;
  const int lane = t & 63, wave = t >> 6;
  const int lrow = lane & 15, quad = lane >> 4;
  const int wr = wave >> 1, wc = wave & 1;
  const int m0 = blockIdx.y * 128, n0 = blockIdx.x * 128;

  const short* pa[2];
  const short* pb[2];
  int wi2[2];
#pragma unroll
  for (int i = 0; i < 2; i++) {
    int wi = wave * 2 + i;
    int row = wi * 16 + (lane >> 2);
    int col = ((lane & 3) ^ (row & 3)) * 8;
    pa[i] = A + (size_t)(m0 + row) * K + col;
    pb[i] = Bw + (size_t)(n0 + row) * K + col;
    wi2[i] = wi;
  }

  floatx4 acc[4][4] = {};
  const int iters = K >> 5;

#pragma unroll
  for (int i = 0; i < 2; i++) {
    async_cp16(pa[i], &As[0][wi2[i] * 512]);
    async_cp16(pb[i], &Bs[0][wi2[i] * 512]);
  }

  for (int it = 0; it < iters; it++) {
    const int cur = it & 1;
    __syncthreads();   // drains stage(it); prior iter's reads of buf[cur^1] done

    if (it + 1 < iters) {
      const int off = (it + 1) * 32;
#pragma unroll
      for (int i = 0; i < 2; i++) {
        async_cp16(pa[i] + off, &As[cur ^ 1][wi2[i] * 512]);
        async_cp16(pb[i] + off, &Bs[cur ^ 1][wi2[i] * 512]);
      }
    }

    bf16x8 af[4], bfr[4];
#pragma unroll
    for (int mt = 0; mt < 4; mt++) {
      int row = wr * 64 + mt * 16 + lrow;
      af[mt] = *(const bf16x8*)&As[cur][row * 32 + (quad ^ (lrow & 3)) * 8];
    }
#pragma unroll
    for (int nt = 0; nt < 4; nt++) {
      int row = wc * 64 + nt * 16 + lrow;
      bfr[nt] = *(const bf16x8*)&Bs[cur][row * 32 + (quad ^ (lrow & 3)) * 8];
    }
#pragma unroll
    for (int mt = 0; mt < 4; mt++)
#pragma unroll
      for (int nt = 0; nt < 4; nt++)
        acc[mt][nt] = __builtin_amdgcn_mfma_f32_16x16x32_bf16(af[mt], bfr[nt],
                                                              acc[mt][nt], 0, 0, 0);
  }

#pragma unroll
  for (int mt = 0; mt < 4; mt++)
#pragma unroll
    for (int nt = 0; nt < 4; nt++) {
      int row = m0 + wr * 64 + mt * 16 + quad * 4;
      int col = n0 + wc * 64 + nt * 16 + lrow;
#pragma unroll
      for (int r = 0; r < 4; r++) {
        if constexpr (std::is_same<OUT, short>::value)
          C[(size_t)(row + r) * N + col] = bf16rn(acc[mt][nt][r]);
        else
          C[(size_t)(row + r) * N + col] = acc[mt][nt][r];
      }
    }
}

// ------------------------------------------- 256x256-tile GEMM (QKV), bf16 out
// R9: same proven 2-barrier/dbuf/gload_lds sync as gemm_bt_as, but 8 waves
// (512 thr) with PER-WAVE output 128x64 -> 2x arithmetic intensity per LDS
// byte (12 KB ds_read per 32 MFMA vs 8 KB per 16). LDS 64 KB (As[2]+Bs[2]
// at 256x32). acc 8x4 floatx4 = 128 VGPR, all static indices (rule #20).
// Catalog datapoint for this structure: 682 TF @4096^3 (m230-V0) vs our
// measured ~435 at 128^2 on these shapes. Grid 12x16 = 192 blocks (75% fill).
__global__ __launch_bounds__(512) void gemm_bt_256(const short* __restrict__ A,
                                                   const short* __restrict__ Bw,
                                                   short* __restrict__ C,
                                                   int N, int K) {
  __shared__ __align__(16) short As[2][256 * 32];
  __shared__ __align__(16) short Bs[2][256 * 32];
  const int t = threadIdx.x;
  const int lane = t & 63, wave = t >> 6;          // wave 0..7
  const int lrow = lane & 15, quad = lane >> 4;
  const int wm = wave >> 2, wn = wave & 3;         // 2M x 4N wave grid
  const int m0 = blockIdx.y * 256, n0 = blockIdx.x * 256;

  // staging: 16 instrs per 16 KB buffer = 2 per wave; same row/col swizzle
  // formula as the 128^2 kernel (store chunk = logical ^ (row&3)).
  const short* pa[2];
  const short* pb[2];
  int wi2[2];
#pragma unroll
  for (int i = 0; i < 2; i++) {
    int wi = wave * 2 + i;                         // 0..15
    int row = wi * 16 + (lane >> 2);               // 0..255
    int col = ((lane & 3) ^ (row & 3)) * 8;
    pa[i] = A + (size_t)(m0 + row) * K + col;
    pb[i] = Bw + (size_t)(n0 + row) * K + col;
    wi2[i] = wi;
  }

  floatx4 acc[8][4] = {};
  const int iters = K >> 5;

#pragma unroll
  for (int i = 0; i < 2; i++) {
    async_cp16(pa[i], &As[0][wi2[i] * 512]);
    async_cp16(pb[i], &Bs[0][wi2[i] * 512]);
  }

  for (int it = 0; it < iters; it++) {
    const int cur = it & 1;
    __syncthreads();   // drains stage(it); prior iter's reads of buf[cur^1] done

    if (it + 1 < iters) {
      const int off = (it + 1) * 32;
#pragma unroll
      for (int i = 0; i < 2; i++) {
        async_cp16(pa[i] + off, &As[cur ^ 1][wi2[i] * 512]);
        async_cp16(pb[i] + off, &Bs[cur ^ 1][wi2[i] * 512]);
      }
    }

    bf16x8 af[8], bfr[4];
#pragma unroll
    for (int mt = 0; mt < 8; mt++) {
      int row = wm * 128 + mt * 16 + lrow;
      af[mt] = *(const bf16x8*)&As[cur][row * 32 + (quad ^ (lrow & 3)) * 8];
    }
#pragma unroll
    for (int nt = 0; nt < 4; nt++) {
      int row = wn * 64 + nt * 16 + lrow;
      bfr[nt] = *(const bf16x8*)&Bs[cur][row * 32 + (quad ^ (lrow & 3)) * 8];
    }
#pragma unroll
    for (int mt = 0; mt < 8; mt++)
#pragma unroll
      for (int nt = 0; nt < 4; nt++)
        acc[mt][nt] = __builtin_amdgcn_mfma_f32_16x16x32_bf16(af[mt], bfr[nt],
                                                              acc[mt][nt], 0, 0, 0);
  }

#pragma unroll
  for (int mt = 0; mt < 8; mt++)
#pragma unroll
    for (int nt = 0; nt < 4; nt++) {
      int row = m0 + wm * 128 + mt * 16 + quad * 4;
      int col = n0 + wn * 64 + nt * 16 + lrow;
#pragma unroll
      for (int r = 0; r < 4; r++)
        C[(size_t)(row + r) * N + col] = bf16rn(acc[mt][nt][r]);
    }
}

// ---------------------------------------------------- rope cos/sin table (once)
// tab[pos*64 + ln] = (cos, sin) of pos * 10000^(-ln/64). Bit-identical math to
// per-element computation, done SEQ*64 times instead of 40x that. (Proven R5.)
__global__ void rope_tab_kern(float2* __restrict__ tab) {
  int i = blockIdx.x * 256 + threadIdx.x;
  int pos = i >> 6, ln = i & 63;
  float fr = (float)pos * exp2f((float)ln * -0.20762050593045935f);
  float s, c;
  sincosf(fr, &s, &c);
  tab[i] = make_float2(c, s);
}

// -------------------------------------------- per-(row,head): RMSNorm+RoPE+gain
// qkv bf16. one wave per (row, slot): slots 0..15 = q heads, 16..19 = k heads
__global__ __launch_bounds__(256) void rms_rope_kern(const short* __restrict__ qkv,
                                                     const float* __restrict__ gain,
                                                     const float2* __restrict__ tab,
                                                     short* __restrict__ qb,
                                                     short* __restrict__ kb) {
  const int t = threadIdx.x;
  const int lane = t & 63, wave = t >> 6;
  const int gw = blockIdx.x * 4 + wave;
  const int row = gw / 20, slot = gw - row * 20;
  const int pos = row & (SEQ - 1);

  const short* src = (slot < 16) ? qkv + (size_t)row * NQKV + slot * HD
                                 : qkv + (size_t)row * NQKV + DIMN + (slot - 16) * HD;
  float x1 = bf2f(src[lane]), x2 = bf2f(src[lane + 64]);

  float ss = x1 * x1 + x2 * x2;
#pragma unroll
  for (int off = 32; off > 0; off >>= 1) ss += __shfl_xor(ss, off);
  float inv = rsqrtf(ss * (1.0f / 128.0f) + 1.1920928955078125e-7f);
  x1 *= inv; x2 *= inv;
  float2 cs = tab[pos * 64 + lane];
  float c = cs.x, s = cs.y;
  float y1 = x1 * c + x2 * s;
  float y2 = x2 * c - x1 * s;
  if (slot < 16) {
    // q_gain * 1/sqrt(HD) * log2(e): softmax then uses exp2 directly
    float g = gain[slot] * 0.12751744459132754f;
    y1 *= g; y2 *= g;
  }
  short o1 = bf16rn(y1), o2 = bf16rn(y2);
  if (slot < 16) { short* d = qb + (size_t)row * DIMN + slot * HD;        d[lane] = o1; d[lane + 64] = o2; }
  else           { short* d = kb + (size_t)row * KVD + (slot - 16) * HD;  d[lane] = o1; d[lane + 64] = o2; }
}

// ------------------------------------- v transpose: qkv bf16 [t][d] -> vT bf16 [d][t]
__global__ __launch_bounds__(256) void vT_kern(const short* __restrict__ qkv,
                                               short* __restrict__ vT) {
  __shared__ short L[64 * 68];
  const int t0 = blockIdx.x * 64, d0 = blockIdx.y * 64;
  const int b = blockIdx.z >> 2, kvh = blockIdx.z & 3;
  const int t = threadIdx.x;

#pragma unroll
  for (int p = 0; p < 4; p++) {
    int tt = p * 16 + (t >> 4);
    int dd = (t & 15) * 4;
    ushort4 v = *(const ushort4*)(qkv + (size_t)(b * SEQ + t0 + tt) * NQKV + VOFF + kvh * HD + d0 + dd);
    *(ushort4*)&L[tt * 68 + dd] = v;
  }
  __syncthreads();

  const int dl = t >> 2;
  const int tc = (t & 3) * 16;
  short tmp[16];
#pragma unroll
  for (int j = 0; j < 16; j++) tmp[j] = L[(tc + j) * 68 + dl];
  size_t obase = (size_t)((b * NKVH + kvh) * HD + d0 + dl) * SEQ + t0 + tc;
  *(uint4*)(vT + obase)     = ((const uint4*)tmp)[0];
  *(uint4*)(vT + obase + 8) = ((const uint4*)tmp)[1];
}

// ------------------------------------------------------- causal flash attention
// FROZEN at best verified state (R7/R8, 85-92 us): swapped-operand MFMA +
// lane-local softmax, Psw bit4=(kw>>2)&1 swizzle, T5 setprio, XCD-aware
// (b,kvh)=id&7 remap (FETCH_SIZE 46->12 MB measured).
__global__ __launch_bounds__(256) void attn_kern(const short* __restrict__ qb,
                                                 const short* __restrict__ kb,
                                                 const short* __restrict__ vT,
                                                 short* __restrict__ yb) {
  __shared__ __align__(16) short Ks[2][64 * 128];   // 32 KB [row][chunk^(row&7)]
  __shared__ __align__(16) short Vs[128 * 64];      // 16 KB [d][chunk^(d&7)]
  __shared__ __align__(16) unsigned Psw[64 * 32];   //  8 KB wave-private P strips
  const int rawid = (int)blockIdx.y * 16 + (int)blockIdx.x;
  const int G = rawid & 7;
  const int rest = rawid >> 3;                      // 0..63
  const int b = G >> 2, kvh = G & 3;
  const int h = kvh * 4 + (rest & 3);
  const int qp = rest >> 2;                         // 0..15
  const int t = threadIdx.x, lane = t & 63, wave = t >> 6;
  const int lrow = lane & 15, quad = lane >> 4;
  const int qrow = wave * 16 + lrow;                // this lane's q-row (0..63)

  int k_row[4], k_col[4], v_row[4], v_col[4];
#pragma unroll
  for (int i = 0; i < 4; i++) {
    int wi = wave * 4 + i;
    int kr = wi * 4 + (lane >> 4);
    k_row[i] = kr; k_col[i] = ((lane & 15) ^ (kr & 7)) * 8;
    int vr = wi * 8 + (lane >> 3);
    v_row[i] = vr; v_col[i] = ((lane & 7) ^ (vr & 7)) * 8;
  }
  const short* kbase = kb + (size_t)b * SEQ * KVD + kvh * HD;
  const short* vbase = vT + (size_t)(b * NKVH + kvh) * HD * SEQ;

  bf16x8 vones;
#pragma unroll
  for (int j = 0; j < 8; j++) vones[j] = (__bf16)1.0f;

  for (int ph = 0; ph < 2; ph++) {
    const int qt = ph ? (31 - qp) : qp;
    const int q0 = qt * 64;

    __syncthreads();  // all waves done with previous phase's LDS reads

    bf16x8 aq[4];
    const short* qrw = qb + (size_t)(b * SEQ + q0 + qrow) * DIMN + h * HD;
#pragma unroll
    for (int kk = 0; kk < 4; kk++)
      aq[kk] = *(const bf16x8*)(qrw + kk * 32 + quad * 8);

    floatx4 O[8] = {};         // O^T: d = n2*16 + quad*4 + r, q = lane&15
    floatx4 Ol = {};           // l accumulator (all 4 rows identical)
    float mI = BIG_NEG;        // per-lane running max for q = lane&15

#pragma unroll
    for (int i = 0; i < 4; i++)
      async_cp16(kbase + (size_t)k_row[i] * KVD + k_col[i], &Ks[0][(wave * 4 + i) * 512]);

    for (int kt = 0; kt <= qt; kt++) {
      const int cur = kt & 1;
      const int k0 = kt * 64;
      __syncthreads();  // drains K(kt); all waves done with Vs(kt-1) reads

#pragma unroll
      for (int i = 0; i < 4; i++)
        async_cp16(vbase + (size_t)v_row[i] * SEQ + k0 + v_col[i], &Vs[(wave * 4 + i) * 512]);
      if (kt < qt) {
        const int kn = k0 + 64;
#pragma unroll
        for (int i = 0; i < 4; i++)
          async_cp16(kbase + (size_t)(kn + k_row[i]) * KVD + k_col[i],
                     &Ks[cur ^ 1][(wave * 4 + i) * 512]);
      }

      floatx4 St[4] = {};
      __builtin_amdgcn_s_setprio(1);
#pragma unroll
      for (int kk = 0; kk < 4; kk++)
#pragma unroll
        for (int nt = 0; nt < 4; nt++) {
          int row = nt * 16 + lrow;
          bf16x8 bk = *(const bf16x8*)&Ks[cur][row * 128 + ((kk * 4 + quad) ^ (row & 7)) * 8];
          St[nt] = __builtin_amdgcn_mfma_f32_16x16x32_bf16(bk, aq[kk], St[nt], 0, 0, 0);
        }
      __builtin_amdgcn_s_setprio(0);

      if (kt == qt) {
#pragma unroll
        for (int nt = 0; nt < 4; nt++)
#pragma unroll
          for (int r = 0; r < 4; r++) {
            int kj = nt * 16 + quad * 4 + r;
            if (kj > qrow) St[nt][r] = BIG_NEG;
          }
      }

      float mx = St[0][0];
#pragma unroll
      for (int nt = 0; nt < 4; nt++)
#pragma unroll
        for (int r = 0; r < 4; r++) mx = fmaxf(mx, St[nt][r]);
      mx = fmaxf(mx, __shfl_xor(mx, 16));
      mx = fmaxf(mx, __shfl_xor(mx, 32));
      if (!__all(mx <= mI + 8.0f)) {
        float mNew = fmaxf(mI, mx);
        float alpha = exp2f(mI - mNew);
        mI = mNew;
#pragma unroll
        for (int n2 = 0; n2 < 8; n2++) O[n2] *= alpha;
        Ol *= alpha;
      }
#pragma unroll
      for (int nt = 0; nt < 4; nt++)
#pragma unroll
        for (int r = 0; r < 4; r++) St[nt][r] = exp2f(St[nt][r] - mI);

#pragma unroll
      for (int nt = 0; nt < 4; nt++)
#pragma unroll
        for (int hh2 = 0; hh2 < 2; hh2++) {
          int kw = nt * 8 + quad * 2 + hh2;
          Psw[qrow * 32 + (kw ^ lrow ^ (((kw >> 2) & 1) << 4))] =
              pack2bf(St[nt][2 * hh2], St[nt][2 * hh2 + 1]);
        }

      __syncthreads();  // drains V(kt) (+K(kt+1)); Vs ready

#pragma unroll
      for (int kk = 0; kk < 2; kk++) {
        union { unsigned u[4]; bf16x8 v; } bp;
#pragma unroll
        for (int j2 = 0; j2 < 4; j2++) {
          int kw = kk * 16 + quad * 4 + j2;
          bp.u[j2] = Psw[qrow * 32 + (kw ^ lrow ^ (((kw >> 2) & 1) << 4))];
        }
        __builtin_amdgcn_s_setprio(1);
#pragma unroll
        for (int n2 = 0; n2 < 8; n2++) {
          int row = n2 * 16 + lrow;
          bf16x8 bv = *(const bf16x8*)&Vs[row * 64 + ((kk * 4 + quad) ^ (row & 7)) * 8];
          O[n2] = __builtin_amdgcn_mfma_f32_16x16x32_bf16(bv, bp.v, O[n2], 0, 0, 0);
        }
        Ol = __builtin_amdgcn_mfma_f32_16x16x32_bf16(vones, bp.v, Ol, 0, 0, 0);
        __builtin_amdgcn_s_setprio(0);
      }
    }

    float il = 1.0f / Ol[0];
    short* yrow = yb + (size_t)(b * SEQ + q0 + qrow) * DIMN + h * HD;
#pragma unroll
    for (int n2 = 0; n2 < 8; n2++) {
      short o[4];
#pragma unroll
      for (int r = 0; r < 4; r++) o[r] = bf16rn(O[n2][r] * il);
      *(uint2*)&yrow[n2 * 16 + quad * 4] = *(const uint2*)o;
    }
  }
}

// ----------------------------------------------------------------- launch
extern "C" void kernel_launch(void* const* d_in, const int* in_sizes, int n_in,
                              void* d_out, int out_size, void* d_ws, size_t ws_size,
                              hipStream_t stream) {
  const float* x      = (const float*)d_in[0];
  const float* q_gain = (const float*)d_in[1];
  const float* W_q    = (const float*)d_in[2];
  const float* W_k    = (const float*)d_in[3];
  const float* W_v    = (const float*)d_in[4];
  const float* W_proj = (const float*)d_in[5];
  float* out = (float*)d_out;
  char* ws = (char*)d_ws;

  short* xb    = (short*)(ws);                // MROWS*DIMN bf16   16.78 MB
  short* wqkv  = (short*)(ws + 16777216);     // NQKV*DIMN bf16    12.58 MB
  short* wproj = (short*)(ws + 29360128);     // DIMN*DIMN bf16     8.39 MB
  short* qkvb  = (short*)(ws + 37748736);     // MROWS*NQKV bf16   25.17 MB
  short* q     = (short*)(ws + 62914560);     // MROWS*DIMN bf16   16.78 MB
  short* k     = (short*)(ws + 79691776);     // MROWS*KVD bf16     4.19 MB
  short* vT    = (short*)(ws + 83886080);     // transposed V bf16  4.19 MB
  short* y     = xb;                          // alias: xb dead after QKV GEMM
  float2* tab  = (float2*)xb;                 // alias: rope table in dead xb

  auto cvt = [&](const float* src, short* dst, int n) {
    int n8 = n / 8;
    f32_to_bf16_kern<<<(n8 + 255) / 256, 256, 0, stream>>>(src, dst, n8);
  };
  cvt(x, xb, MROWS * DIMN);
  cvt(W_q, wqkv, DIMN * DIMN);
  cvt(W_k, wqkv + DIMN * DIMN, KVD * DIMN);
  cvt(W_v, wqkv + DIMN * DIMN + KVD * DIMN, KVD * DIMN);
  cvt(W_proj, wproj, DIMN * DIMN);

  // qkv (bf16) = x @ [Wq;Wk;Wv]^T   -- 256^2-tile high-intensity GEMM
  gemm_bt_256<<<dim3(NQKV / 256, MROWS / 256), 512, 0, stream>>>(xb, wqkv, qkvb, NQKV, DIMN);
  // rope table into (now dead) xb region, then norm+rope
  rope_tab_kern<<<(SEQ * 64) / 256, 256, 0, stream>>>(tab);
  rms_rope_kern<<<(MROWS * 20) / 4, 256, 0, stream>>>(qkvb, q_gain, tab, q, k);
  vT_kern<<<dim3(SEQ / 64, HD / 64, BATCH * NKVH), 256, 0, stream>>>(qkvb, vT);
  attn_kern<<<dim3(16, 32), 256, 0, stream>>>(q, k, vT, y);
  // out (f32) = y @ Wproj^T  -- stays 128^2 (256^2 would be 50% CU fill)
  gemm_bt_as<float><<<dim3(DIMN / 128, MROWS / 128), 256, 0, stream>>>(y, wproj, out, DIMN, DIMN);
}

// Round 10
// 313.362 us; speedup vs baseline: 1.1167x; 1.1167x over previous
//
#include <hip/hip_runtime.h>
#include <hip/hip_bf16.h>
#include <type_traits>

// Problem constants
#define DIMN   2048
#define NH     16
#define NKVH   4
#define HD     128
#define KVD    512        // NKVH*HD
#define NQKV   3072       // DIMN + 2*KVD
#define BATCH  2
#define SEQ    2048
#define MROWS  4096       // BATCH*SEQ
#define VOFF   2560       // DIMN + KVD: v offset inside qkv row

// cvt segment sizes in 8-float units
#define N8_X   (MROWS * DIMN / 8)     // 1048576
#define N8_WQ  (DIMN * DIMN / 8)      //  524288
#define N8_WKV (KVD * DIMN / 8)       //  131072
#define N8_ALL (N8_X + N8_WQ + 2 * N8_WKV + N8_WQ)   // 2359296

typedef __attribute__((ext_vector_type(8))) __bf16 bf16x8;
typedef __attribute__((ext_vector_type(4))) float floatx4;

#define BIG_NEG (-1.0e30f)

// hardware RTNE f32->bf16 (v_cvt_pk_bf16_f32)
__device__ __forceinline__ short bf16rn(float f) {
  union { __bf16 h; short s; } u;
  u.h = (__bf16)f;
  return u.s;
}
__device__ __forceinline__ float bf2f(short s) {
  union { unsigned u; float f; } v;
  v.u = ((unsigned)(unsigned short)s) << 16;
  return v.f;
}
__device__ __forceinline__ unsigned pack2bf(float a, float b) {
  return (unsigned)(unsigned short)bf16rn(a) |
         ((unsigned)(unsigned short)bf16rn(b) << 16);
}

// async 16B global -> LDS. LDS dest = wave-uniform base + lane*16 B;
// one instruction covers 64 lanes * 16 B = 512 shorts.
__device__ __forceinline__ void async_cp16(const short* g, short* l) {
  __builtin_amdgcn_global_load_lds(
      (const __attribute__((address_space(1))) unsigned int*)g,
      (__attribute__((address_space(3))) unsigned int*)l, 16, 0, 0);
}

// ------------------------------------------------- f32 -> bf16, ALL 5 tensors
// R10: one launch instead of five (same math/bytes; removes 4 launch ramps).
__global__ __launch_bounds__(256) void cvt_all_kern(const float* __restrict__ x,
                                                    const float* __restrict__ wq,
                                                    const float* __restrict__ wk,
                                                    const float* __restrict__ wv,
                                                    const float* __restrict__ wp,
                                                    short* __restrict__ xb,
                                                    short* __restrict__ wqkv,
                                                    short* __restrict__ wproj) {
  int i = blockIdx.x * 256 + threadIdx.x;
  if (i >= N8_ALL) return;
  const float* src; short* dst; int j;
  if (i < N8_X)                      { src = x;  dst = xb;    j = i; }
  else if (i < N8_X + N8_WQ)         { src = wq; dst = wqkv;  j = i - N8_X; }
  else if (i < N8_X + N8_WQ + N8_WKV){ src = wk; dst = wqkv + DIMN * DIMN;
                                       j = i - (N8_X + N8_WQ); }
  else if (i < N8_X + N8_WQ + 2 * N8_WKV)
                                     { src = wv; dst = wqkv + DIMN * DIMN + KVD * DIMN;
                                       j = i - (N8_X + N8_WQ + N8_WKV); }
  else                               { src = wp; dst = wproj;
                                       j = i - (N8_X + N8_WQ + 2 * N8_WKV); }
  float4 a = ((const float4*)src)[j * 2];
  float4 b = ((const float4*)src)[j * 2 + 1];
  short r[8];
  r[0] = bf16rn(a.x); r[1] = bf16rn(a.y); r[2] = bf16rn(a.z); r[3] = bf16rn(a.w);
  r[4] = bf16rn(b.x); r[5] = bf16rn(b.y); r[6] = bf16rn(b.z); r[7] = bf16rn(b.w);
  ((uint4*)dst)[j] = *(const uint4*)r;
}

// --------------------------------------------------- C[M][N] = A[M][K] B[N][K]^T
// 128x128 tile, BK=32, double-buffered global_load_lds staging, one barrier per
// K-iter. XOR-swizzled LDS (stored chunk = logical ^ (row&3)). OUT: float or
// bf16 (short) epilogue. R10: 256^2 QKV variant REVERTED (R9: 192 blocks = 75%
// fill, <=1 block/CU -> no co-resident overlap, FETCH 2.7x, 534 TF vs this
// kernel's ~746 TF measured at the QKV shape). Natural n&7 XCD mapping keeps
// B-panels L2-resident (R7/R8 measured) - do not swizzle.
template <typename OUT>
__global__ __launch_bounds__(256) void gemm_bt_as(const short* __restrict__ A,
                                                  const short* __restrict__ Bw,
                                                  OUT* __restrict__ C,
                                                  int N, int K) {
  __shared__ __align__(16) short As[2][128 * 32];
  __shared__ __align__(16) short Bs[2][128 * 32];
  const int t = threadIdx.x;
  const int lane = t & 63, wave = t >> 6;
  const int lrow = lane & 15, quad = lane >> 4;
  const int wr = wave >> 1, wc = wave & 1;
  const int m0 = blockIdx.y * 128, n0 = blockIdx.x * 128;

  const short* pa[2];
  const short* pb[2];
  int wi2[2];
#pragma unroll
  for (int i = 0; i < 2; i++) {
    int wi = wave * 2 + i;
    int row = wi * 16 + (lane >> 2);
    int col = ((lane & 3) ^ (row & 3)) * 8;
    pa[i] = A + (size_t)(m0 + row) * K + col;
    pb[i] = Bw + (size_t)(n0 + row) * K + col;
    wi2[i] = wi;
  }

  floatx4 acc[4][4] = {};
  const int iters = K >> 5;

#pragma unroll
  for (int i = 0; i < 2; i++) {
    async_cp16(pa[i], &As[0][wi2[i] * 512]);
    async_cp16(pb[i], &Bs[0][wi2[i] * 512]);
  }

  for (int it = 0; it < iters; it++) {
    const int cur = it & 1;
    __syncthreads();   // drains stage(it); prior iter's reads of buf[cur^1] done

    if (it + 1 < iters) {
      const int off = (it + 1) * 32;
#pragma unroll
      for (int i = 0; i < 2; i++) {
        async_cp16(pa[i] + off, &As[cur ^ 1][wi2[i] * 512]);
        async_cp16(pb[i] + off, &Bs[cur ^ 1][wi2[i] * 512]);
      }
    }

    bf16x8 af[4], bfr[4];
#pragma unroll
    for (int mt = 0; mt < 4; mt++) {
      int row = wr * 64 + mt * 16 + lrow;
      af[mt] = *(const bf16x8*)&As[cur][row * 32 + (quad ^ (lrow & 3)) * 8];
    }
#pragma unroll
    for (int nt = 0; nt < 4; nt++) {
      int row = wc * 64 + nt * 16 + lrow;
      bfr[nt] = *(const bf16x8*)&Bs[cur][row * 32 + (quad ^ (lrow & 3)) * 8];
    }
#pragma unroll
    for (int mt = 0; mt < 4; mt++)
#pragma unroll
      for (int nt = 0; nt < 4; nt++)
        acc[mt][nt] = __builtin_amdgcn_mfma_f32_16x16x32_bf16(af[mt], bfr[nt],
                                                              acc[mt][nt], 0, 0, 0);
  }

#pragma unroll
  for (int mt = 0; mt < 4; mt++)
#pragma unroll
    for (int nt = 0; nt < 4; nt++) {
      int row = m0 + wr * 64 + mt * 16 + quad * 4;
      int col = n0 + wc * 64 + nt * 16 + lrow;
#pragma unroll
      for (int r = 0; r < 4; r++) {
        if constexpr (std::is_same<OUT, short>::value)
          C[(size_t)(row + r) * N + col] = bf16rn(acc[mt][nt][r]);
        else
          C[(size_t)(row + r) * N + col] = acc[mt][nt][r];
      }
    }
}

// ---------------------------------------------------- rope cos/sin table (once)
// tab[pos*64 + ln] = (cos, sin) of pos * 10000^(-ln/64). Bit-identical math to
// per-element computation, done SEQ*64 times instead of 40x that. (Proven R5.)
__global__ void rope_tab_kern(float2* __restrict__ tab) {
  int i = blockIdx.x * 256 + threadIdx.x;
  int pos = i >> 6, ln = i & 63;
  float fr = (float)pos * exp2f((float)ln * -0.20762050593045935f);
  float s, c;
  sincosf(fr, &s, &c);
  tab[i] = make_float2(c, s);
}

// -------------------------------------------- per-(row,head): RMSNorm+RoPE+gain
// qkv bf16. one wave per (row, slot): slots 0..15 = q heads, 16..19 = k heads
__global__ __launch_bounds__(256) void rms_rope_kern(const short* __restrict__ qkv,
                                                     const float* __restrict__ gain,
                                                     const float2* __restrict__ tab,
                                                     short* __restrict__ qb,
                                                     short* __restrict__ kb) {
  const int t = threadIdx.x;
  const int lane = t & 63, wave = t >> 6;
  const int gw = blockIdx.x * 4 + wave;
  const int row = gw / 20, slot = gw - row * 20;
  const int pos = row & (SEQ - 1);

  const short* src = (slot < 16) ? qkv + (size_t)row * NQKV + slot * HD
                                 : qkv + (size_t)row * NQKV + DIMN + (slot - 16) * HD;
  float x1 = bf2f(src[lane]), x2 = bf2f(src[lane + 64]);

  float ss = x1 * x1 + x2 * x2;
#pragma unroll
  for (int off = 32; off > 0; off >>= 1) ss += __shfl_xor(ss, off);
  float inv = rsqrtf(ss * (1.0f / 128.0f) + 1.1920928955078125e-7f);
  x1 *= inv; x2 *= inv;
  float2 cs = tab[pos * 64 + lane];
  float c = cs.x, s = cs.y;
  float y1 = x1 * c + x2 * s;
  float y2 = x2 * c - x1 * s;
  if (slot < 16) {
    // q_gain * 1/sqrt(HD) * log2(e): softmax then uses exp2 directly
    float g = gain[slot] * 0.12751744459132754f;
    y1 *= g; y2 *= g;
  }
  short o1 = bf16rn(y1), o2 = bf16rn(y2);
  if (slot < 16) { short* d = qb + (size_t)row * DIMN + slot * HD;        d[lane] = o1; d[lane + 64] = o2; }
  else           { short* d = kb + (size_t)row * KVD + (slot - 16) * HD;  d[lane] = o1; d[lane + 64] = o2; }
}

// ------------------------------------- v transpose: qkv bf16 [t][d] -> vT bf16 [d][t]
__global__ __launch_bounds__(256) void vT_kern(const short* __restrict__ qkv,
                                               short* __restrict__ vT) {
  __shared__ short L[64 * 68];
  const int t0 = blockIdx.x * 64, d0 = blockIdx.y * 64;
  const int b = blockIdx.z >> 2, kvh = blockIdx.z & 3;
  const int t = threadIdx.x;

#pragma unroll
  for (int p = 0; p < 4; p++) {
    int tt = p * 16 + (t >> 4);
    int dd = (t & 15) * 4;
    ushort4 v = *(const ushort4*)(qkv + (size_t)(b * SEQ + t0 + tt) * NQKV + VOFF + kvh * HD + d0 + dd);
    *(ushort4*)&L[tt * 68 + dd] = v;
  }
  __syncthreads();

  const int dl = t >> 2;
  const int tc = (t & 3) * 16;
  short tmp[16];
#pragma unroll
  for (int j = 0; j < 16; j++) tmp[j] = L[(tc + j) * 68 + dl];
  size_t obase = (size_t)((b * NKVH + kvh) * HD + d0 + dl) * SEQ + t0 + tc;
  *(uint4*)(vT + obase)     = ((const uint4*)tmp)[0];
  *(uint4*)(vT + obase + 8) = ((const uint4*)tmp)[1];
}

// ------------------------------------------------------- causal flash attention
// FROZEN at best verified state (R7/R8, 85-92 us): swapped-operand MFMA +
// lane-local softmax, Psw bit4=(kw>>2)&1 swizzle, T5 setprio, XCD-aware
// (b,kvh)=id&7 remap (FETCH_SIZE 46->12 MB measured).
__global__ __launch_bounds__(256) void attn_kern(const short* __restrict__ qb,
                                                 const short* __restrict__ kb,
                                                 const short* __restrict__ vT,
                                                 short* __restrict__ yb) {
  __shared__ __align__(16) short Ks[2][64 * 128];   // 32 KB [row][chunk^(row&7)]
  __shared__ __align__(16) short Vs[128 * 64];      // 16 KB [d][chunk^(d&7)]
  __shared__ __align__(16) unsigned Psw[64 * 32];   //  8 KB wave-private P strips
  const int rawid = (int)blockIdx.y * 16 + (int)blockIdx.x;
  const int G = rawid & 7;
  const int rest = rawid >> 3;                      // 0..63
  const int b = G >> 2, kvh = G & 3;
  const int h = kvh * 4 + (rest & 3);
  const int qp = rest >> 2;                         // 0..15
  const int t = threadIdx.x, lane = t & 63, wave = t >> 6;
  const int lrow = lane & 15, quad = lane >> 4;
  const int qrow = wave * 16 + lrow;                // this lane's q-row (0..63)

  int k_row[4], k_col[4], v_row[4], v_col[4];
#pragma unroll
  for (int i = 0; i < 4; i++) {
    int wi = wave * 4 + i;
    int kr = wi * 4 + (lane >> 4);
    k_row[i] = kr; k_col[i] = ((lane & 15) ^ (kr & 7)) * 8;
    int vr = wi * 8 + (lane >> 3);
    v_row[i] = vr; v_col[i] = ((lane & 7) ^ (vr & 7)) * 8;
  }
  const short* kbase = kb + (size_t)b * SEQ * KVD + kvh * HD;
  const short* vbase = vT + (size_t)(b * NKVH + kvh) * HD * SEQ;

  bf16x8 vones;
#pragma unroll
  for (int j = 0; j < 8; j++) vones[j] = (__bf16)1.0f;

  for (int ph = 0; ph < 2; ph++) {
    const int qt = ph ? (31 - qp) : qp;
    const int q0 = qt * 64;

    __syncthreads();  // all waves done with previous phase's LDS reads

    bf16x8 aq[4];
    const short* qrw = qb + (size_t)(b * SEQ + q0 + qrow) * DIMN + h * HD;
#pragma unroll
    for (int kk = 0; kk < 4; kk++)
      aq[kk] = *(const bf16x8*)(qrw + kk * 32 + quad * 8);

    floatx4 O[8] = {};         // O^T: d = n2*16 + quad*4 + r, q = lane&15
    floatx4 Ol = {};           // l accumulator (all 4 rows identical)
    float mI = BIG_NEG;        // per-lane running max for q = lane&15

#pragma unroll
    for (int i = 0; i < 4; i++)
      async_cp16(kbase + (size_t)k_row[i] * KVD + k_col[i], &Ks[0][(wave * 4 + i) * 512]);

    for (int kt = 0; kt <= qt; kt++) {
      const int cur = kt & 1;
      const int k0 = kt * 64;
      __syncthreads();  // drains K(kt); all waves done with Vs(kt-1) reads

#pragma unroll
      for (int i = 0; i < 4; i++)
        async_cp16(vbase + (size_t)v_row[i] * SEQ + k0 + v_col[i], &Vs[(wave * 4 + i) * 512]);
      if (kt < qt) {
        const int kn = k0 + 64;
#pragma unroll
        for (int i = 0; i < 4; i++)
          async_cp16(kbase + (size_t)(kn + k_row[i]) * KVD + k_col[i],
                     &Ks[cur ^ 1][(wave * 4 + i) * 512]);
      }

      floatx4 St[4] = {};
      __builtin_amdgcn_s_setprio(1);
#pragma unroll
      for (int kk = 0; kk < 4; kk++)
#pragma unroll
        for (int nt = 0; nt < 4; nt++) {
          int row = nt * 16 + lrow;
          bf16x8 bk = *(const bf16x8*)&Ks[cur][row * 128 + ((kk * 4 + quad) ^ (row & 7)) * 8];
          St[nt] = __builtin_amdgcn_mfma_f32_16x16x32_bf16(bk, aq[kk], St[nt], 0, 0, 0);
        }
      __builtin_amdgcn_s_setprio(0);

      if (kt == qt) {
#pragma unroll
        for (int nt = 0; nt < 4; nt++)
#pragma unroll
          for (int r = 0; r < 4; r++) {
            int kj = nt * 16 + quad * 4 + r;
            if (kj > qrow) St[nt][r] = BIG_NEG;
          }
      }

      float mx = St[0][0];
#pragma unroll
      for (int nt = 0; nt < 4; nt++)
#pragma unroll
        for (int r = 0; r < 4; r++) mx = fmaxf(mx, St[nt][r]);
      mx = fmaxf(mx, __shfl_xor(mx, 16));
      mx = fmaxf(mx, __shfl_xor(mx, 32));
      if (!__all(mx <= mI + 8.0f)) {
        float mNew = fmaxf(mI, mx);
        float alpha = exp2f(mI - mNew);
        mI = mNew;
#pragma unroll
        for (int n2 = 0; n2 < 8; n2++) O[n2] *= alpha;
        Ol *= alpha;
      }
#pragma unroll
      for (int nt = 0; nt < 4; nt++)
#pragma unroll
        for (int r = 0; r < 4; r++) St[nt][r] = exp2f(St[nt][r] - mI);

#pragma unroll
      for (int nt = 0; nt < 4; nt++)
#pragma unroll
        for (int hh2 = 0; hh2 < 2; hh2++) {
          int kw = nt * 8 + quad * 2 + hh2;
          Psw[qrow * 32 + (kw ^ lrow ^ (((kw >> 2) & 1) << 4))] =
              pack2bf(St[nt][2 * hh2], St[nt][2 * hh2 + 1]);
        }

      __syncthreads();  // drains V(kt) (+K(kt+1)); Vs ready

#pragma unroll
      for (int kk = 0; kk < 2; kk++) {
        union { unsigned u[4]; bf16x8 v; } bp;
#pragma unroll
        for (int j2 = 0; j2 < 4; j2++) {
          int kw = kk * 16 + quad * 4 + j2;
          bp.u[j2] = Psw[qrow * 32 + (kw ^ lrow ^ (((kw >> 2) & 1) << 4))];
        }
        __builtin_amdgcn_s_setprio(1);
#pragma unroll
        for (int n2 = 0; n2 < 8; n2++) {
          int row = n2 * 16 + lrow;
          bf16x8 bv = *(const bf16x8*)&Vs[row * 64 + ((kk * 4 + quad) ^ (row & 7)) * 8];
          O[n2] = __builtin_amdgcn_mfma_f32_16x16x32_bf16(bv, bp.v, O[n2], 0, 0, 0);
        }
        Ol = __builtin_amdgcn_mfma_f32_16x16x32_bf16(vones, bp.v, Ol, 0, 0, 0);
        __builtin_amdgcn_s_setprio(0);
      }
    }

    float il = 1.0f / Ol[0];
    short* yrow = yb + (size_t)(b * SEQ + q0 + qrow) * DIMN + h * HD;
#pragma unroll
    for (int n2 = 0; n2 < 8; n2++) {
      short o[4];
#pragma unroll
      for (int r = 0; r < 4; r++) o[r] = bf16rn(O[n2][r] * il);
      *(uint2*)&yrow[n2 * 16 + quad * 4] = *(const uint2*)o;
    }
  }
}

// ----------------------------------------------------------------- launch
extern "C" void kernel_launch(void* const* d_in, const int* in_sizes, int n_in,
                              void* d_out, int out_size, void* d_ws, size_t ws_size,
                              hipStream_t stream) {
  const float* x      = (const float*)d_in[0];
  const float* q_gain = (const float*)d_in[1];
  const float* W_q    = (const float*)d_in[2];
  const float* W_k    = (const float*)d_in[3];
  const float* W_v    = (const float*)d_in[4];
  const float* W_proj = (const float*)d_in[5];
  float* out = (float*)d_out;
  char* ws = (char*)d_ws;

  short* xb    = (short*)(ws);                // MROWS*DIMN bf16   16.78 MB
  short* wqkv  = (short*)(ws + 16777216);     // NQKV*DIMN bf16    12.58 MB
  short* wproj = (short*)(ws + 29360128);     // DIMN*DIMN bf16     8.39 MB
  short* qkvb  = (short*)(ws + 37748736);     // MROWS*NQKV bf16   25.17 MB
  short* q     = (short*)(ws + 62914560);     // MROWS*DIMN bf16   16.78 MB
  short* k     = (short*)(ws + 79691776);     // MROWS*KVD bf16     4.19 MB
  short* vT    = (short*)(ws + 83886080);     // transposed V bf16  4.19 MB
  short* y     = xb;                          // alias: xb dead after QKV GEMM
  float2* tab  = (float2*)xb;                 // alias: rope table in dead xb

  // single fused conversion pass (R10; was 5 launches)
  cvt_all_kern<<<(N8_ALL + 255) / 256, 256, 0, stream>>>(
      x, W_q, W_k, W_v, W_proj, xb, wqkv, wproj);

  // qkv (bf16) = x @ [Wq;Wk;Wv]^T  -- proven 128^2 kernel (~69 us, ~746 TF)
  gemm_bt_as<short><<<dim3(NQKV / 128, MROWS / 128), 256, 0, stream>>>(xb, wqkv, qkvb, NQKV, DIMN);
  // rope table into (now dead) xb region, then norm+rope
  rope_tab_kern<<<(SEQ * 64) / 256, 256, 0, stream>>>(tab);
  rms_rope_kern<<<(MROWS * 20) / 4, 256, 0, stream>>>(qkvb, q_gain, tab, q, k);
  vT_kern<<<dim3(SEQ / 64, HD / 64, BATCH * NKVH), 256, 0, stream>>>(qkvb, vT);
  attn_kern<<<dim3(16, 32), 256, 0, stream>>>(q, k, vT, y);
  // out (f32) = y @ Wproj^T
  gemm_bt_as<float><<<dim3(DIMN / 128, MROWS / 128), 256, 0, stream>>>(y, wproj, out, DIMN, DIMN);
}